// Round 8
// baseline (289.875 us; speedup 1.0000x reference)
//
#include <hip/hip_runtime.h>

// MHA fwd: B=2 S=2048 D=1024 H=16 HD=64, all-bf16 MFMA pipeline.
// ws (32MB, ushort units): Qh @0 (4M) | Kh @4M (4M) | Vt @8M (4M) | ctx @12M (4M)
// d_out (8M ushorts): qb@0 + kb@4M during QK; then vb@0 for V; then final fp32 out.
// Weights are read as fp32 DIRECTLY by the GEMMs (converted in the pipelined B-staging
// path) -- no weight conversion kernels, no weight scratch.
//
// GEMM K-loop (r8): attn-proven issue-ahead double-buffer.
//   writeB(tile it from regs) ; barrier (drains A-DMA(it) issued LAST iter + all ds_writes)
//   issue A-DMA(it+1) + W-loads(it+1)   <- one full compute phase of slack
//   compute tile it
// A: global_load_lds w16, swizzled chunk layout (slot = r*8 + (qc^(r&7)), frag reads 2-way).
// B: fp32 -> regs (prefetched) -> bf16 pack -> ds_write, padded row-major LD=72.
// 51KB LDS -> 3 blocks/CU (m97-class co-residency) with in-block overlap on top.

typedef __attribute__((ext_vector_type(8))) short short8;
typedef __attribute__((ext_vector_type(4))) float f32x4;
typedef __attribute__((ext_vector_type(4))) int int32x4;

#define MFMA16(a, b, c) __builtin_amdgcn_mfma_f32_16x16x32_bf16(a, b, c, 0, 0, 0)

#define GLL16(gp, lp) __builtin_amdgcn_global_load_lds( \
    (const __attribute__((address_space(1))) void*)(gp), \
    (__attribute__((address_space(3))) void*)(lp), 16, 0, 0)

static __device__ __forceinline__ unsigned short f2bf(float x) {
    unsigned int u = __float_as_uint(x);
    u = (u + 0x7fffu + ((u >> 16) & 1u)) >> 16;
    return (unsigned short)u;
}

// ---------------- fp32 -> bf16 input converts ----------------
__global__ __launch_bounds__(256)
void conv_cast2(const float* __restrict__ s0, unsigned short* __restrict__ d0,
                const float* __restrict__ s1, unsigned short* __restrict__ d1)
{
    const float* s = blockIdx.y ? s1 : s0;
    unsigned short* d = blockIdx.y ? d1 : d0;
    const int i = (blockIdx.x * 256 + threadIdx.x) * 8;
    const float4 a = *(const float4*)(s + i);
    const float4 b = *(const float4*)(s + i + 4);
    ushort4 lo, hi;
    lo.x = f2bf(a.x); lo.y = f2bf(a.y); lo.z = f2bf(a.z); lo.w = f2bf(a.w);
    hi.x = f2bf(b.x); hi.y = f2bf(b.y); hi.z = f2bf(b.z); hi.w = f2bf(b.w);
    *(ushort4*)(d + i) = lo;
    *(ushort4*)(d + i + 4) = hi;
}

// ---------------- bf16 GEMM core: C[i][j] = alpha*(sum_k A[i][k] W[j][k] + bias[j]) ----------
// Tile 128x64, BK=64. A bf16 (DMA dbuf), W fp32 (reg-prefetch dbuf). sub in [0,512).
// sm layout (ushorts): Abuf0 @0 (8192) | Abuf1 @8192 | Bbuf0 @16384 (4608) | Bbuf1 @20992
// OUT_MODE 0: fp32 [4096][1024]; 1: bf16 [B][H][S][64]; 2: bf16 [B][H][64][S]
template<int OUT_MODE>
static __device__ __forceinline__
void gemm_core(int sub, const unsigned short* __restrict__ A, const float* __restrict__ Wf,
               const float* __restrict__ bias, float alpha, void* __restrict__ outp,
               unsigned short* sm)   // 25600 ushorts = 51.2KB
{
    constexpr int N = 1024, K = 1024;
    const int xcd = sub & 7, loc = sub >> 3;          // loc 0..63
    const int m0 = (xcd * 4 + (loc >> 4)) * 128;      // 32 m-tiles
    const int n0 = (loc & 15) * 64;                   // 16 n-tiles

    const int tid = threadIdx.x, lane = tid & 63, wave = tid >> 6;
    const int lr = lane & 15, quad = lane >> 4;
    const int wm = (wave >> 1) * 64, wn = (wave & 1) * 32;

    f32x4 acc[4][2];
#pragma unroll
    for (int mt = 0; mt < 4; mt++)
#pragma unroll
        for (int nt = 0; nt < 2; nt++) acc[mt][nt] = (f32x4){0.f, 0.f, 0.f, 0.f};

    const int lr3 = lane >> 3;            // 0..7
    const int qcs = (lane & 7) ^ lr3;     // swizzled DMA source chunk

    auto stageA = [&](unsigned short* Ab, int k0) {
#pragma unroll
        for (int n = 0; n < 4; n++) {
            const int W = wave * 4 + n;   // 0..15
            const int row = W * 8 + lr3;  // 0..127
            GLL16(A + (size_t)(m0 + row) * K + k0 + qcs * 8, Ab + W * 512);
        }
    };

    const int brow = tid >> 2, bseg = tid & 3;        // 64 rows x 4 segs of 16 floats
    float4 wreg[4];
    auto loadW = [&](int k0) {
        const float* wsrc = Wf + (size_t)(n0 + brow) * K + k0 + bseg * 16;
        wreg[0] = *(const float4*)(wsrc);
        wreg[1] = *(const float4*)(wsrc + 4);
        wreg[2] = *(const float4*)(wsrc + 8);
        wreg[3] = *(const float4*)(wsrc + 12);
    };
    auto writeB = [&](unsigned short* Bb) {
        unsigned u[8];
#pragma unroll
        for (int i = 0; i < 4; i++) {
            u[2 * i]     = ((unsigned)f2bf(wreg[i].y) << 16) | f2bf(wreg[i].x);
            u[2 * i + 1] = ((unsigned)f2bf(wreg[i].w) << 16) | f2bf(wreg[i].z);
        }
        int32x4 v0 = (int32x4){(int)u[0], (int)u[1], (int)u[2], (int)u[3]};
        int32x4 v1 = (int32x4){(int)u[4], (int)u[5], (int)u[6], (int)u[7]};
        *(int32x4*)&Bb[brow * 72 + bseg * 16] = v0;
        *(int32x4*)&Bb[brow * 72 + bseg * 16 + 8] = v1;
    };

    stageA(sm, 0);      // A tile 0 -> Abuf0
    loadW(0);           // W tile 0 -> regs

    for (int it = 0; it < 16; ++it) {
        const int c = it & 1;
        unsigned short* Ab = sm + c * 8192;
        unsigned short* Bb = sm + 16384 + c * 4608;
        writeB(Bb);                      // tile it weights regs->LDS (vmcnt: loads are 1 phase old)
        __syncthreads();                 // drains A-DMA(it) (issued last iter) + all ds_writes
        if (it + 1 < 16) {
            stageA(sm + (c ^ 1) * 8192, (it + 1) * 64);   // in flight across compute(it)
            loadW((it + 1) * 64);
        }
#pragma unroll
        for (int kc = 0; kc < 2; kc++) {
            short8 af[4], bfr[2];
#pragma unroll
            for (int mt = 0; mt < 4; mt++) {
                const int r = wm + mt * 16 + lr;
                af[mt] = *(const short8*)&Ab[(r * 8 + ((kc * 4 + quad) ^ (r & 7))) * 8];
            }
#pragma unroll
            for (int nt = 0; nt < 2; nt++)
                bfr[nt] = *(const short8*)&Bb[(wn + nt * 16 + lr) * 72 + kc * 32 + quad * 8];
#pragma unroll
            for (int mt = 0; mt < 4; mt++)
#pragma unroll
                for (int nt = 0; nt < 2; nt++)
                    acc[mt][nt] = MFMA16(af[mt], bfr[nt], acc[mt][nt]);
        }
    }

    if constexpr (OUT_MODE == 2) {
        // V^T: transpose 128(s) x 64(dd) via LDS, coalesced stores.
        constexpr int LDT = 136;
        __syncthreads();
        unsigned short* Ts = sm;          // 64*136*2 = 17408 B
#pragma unroll
        for (int mt = 0; mt < 4; mt++)
#pragma unroll
            for (int nt = 0; nt < 2; nt++) {
                const int dd = wn + nt * 16 + lr;
                const int ss = wm + mt * 16 + quad * 4;
                const int j = n0 + dd;
                ushort4 tv;
                tv.x = f2bf(alpha * (acc[mt][nt][0] + bias[j]));
                tv.y = f2bf(alpha * (acc[mt][nt][1] + bias[j]));
                tv.z = f2bf(alpha * (acc[mt][nt][2] + bias[j]));
                tv.w = f2bf(alpha * (acc[mt][nt][3] + bias[j]));
                *(ushort4*)&Ts[dd * LDT + ss] = tv;
            }
        __syncthreads();
        const int b = m0 >> 11, hh = (n0 >> 6) & 15, sbase = m0 & 2047;
        const int row = tid >> 2, c4 = (tid & 3) * 32;
        unsigned short* dst = (unsigned short*)outp
            + (((size_t)(b * 16 + hh) * 64) + row) * 2048 + sbase + c4;
#pragma unroll
        for (int t = 0; t < 4; ++t)
            *(short8*)&dst[t * 8] = *(const short8*)&Ts[row * LDT + c4 + t * 8];
        return;
    }

#pragma unroll
    for (int mt = 0; mt < 4; mt++)
#pragma unroll
        for (int nt = 0; nt < 2; nt++)
#pragma unroll
            for (int r = 0; r < 4; r++) {
                const int i = m0 + wm + mt * 16 + quad * 4 + r;
                const int j = n0 + wn + nt * 16 + lr;
                const float val = alpha * (acc[mt][nt][r] + bias[j]);
                if constexpr (OUT_MODE == 0) {
                    ((float*)outp)[(size_t)i * N + j] = val;
                } else {
                    const int b = i >> 11, s = i & 2047, hh = j >> 6, dd = j & 63;
                    ((unsigned short*)outp)[(((size_t)(b * 16 + hh) * 2048) + s) * 64 + dd] = f2bf(val);
                }
            }
}

// fused Q+K projections: 1024 blocks. id<512 -> Q (alpha_q), else K.
__global__ __launch_bounds__(256)
void gemm_qk(const unsigned short* __restrict__ qb, const float* __restrict__ Wq,
             const float* __restrict__ bq, float alpha_q, void* __restrict__ Qh,
             const unsigned short* __restrict__ kb, const float* __restrict__ Wk,
             const float* __restrict__ bk, void* __restrict__ Kh)
{
    __shared__ unsigned short sm[25600];
    const int id = blockIdx.x, sub = id & 511;
    if (id < 512) gemm_core<1>(sub, qb, Wq, bq, alpha_q, Qh, sm);
    else          gemm_core<1>(sub, kb, Wk, bk, 1.0f,   Kh, sm);
}

template<int OUT_MODE>
__global__ __launch_bounds__(256)
void gemm_one(const unsigned short* __restrict__ A, const float* __restrict__ Wf,
              const float* __restrict__ bias, float alpha, void* __restrict__ outp)
{
    __shared__ unsigned short sm[25600];
    gemm_core<OUT_MODE>(blockIdx.x, A, Wf, bias, alpha, outp, sm);
}

// ---------------- attention (unchanged: proven 89 us control) ----------------
__global__ __launch_bounds__(256)
void attn_kernel(const unsigned short* __restrict__ Qh, const unsigned short* __restrict__ Kh,
                 const unsigned short* __restrict__ Vt, const int* __restrict__ kpm,
                 const int* __restrict__ am, unsigned short* __restrict__ ctx)
{
    const int qb = blockIdx.x, bh = blockIdx.y, b = bh >> 4, h = bh & 15;
    const int q0 = qb * 64;
    const int tid = threadIdx.x, lane = tid & 63, wave = tid >> 6;
    const int lr = lane & 15, quad = lane >> 4;

    __shared__ unsigned short Ks[2][64 * 64];
    __shared__ unsigned short Vs[2][64 * 64];
    __shared__ float maskl[2048];

    for (int i = tid; i < 2048; i += 256)
        maskl[i] = (kpm[b * 2048 + i] | am[b * 2048 + i]) ? 0.f : 1.f;

    const unsigned short* Kbh = Kh + (size_t)bh * 2048 * 64;
    const unsigned short* Vbh = Vt + (size_t)bh * 64 * 2048;

    const int lr3 = lane >> 3;
    const int qcs = (lane & 7) ^ lr3;

    auto stage = [&](int buf, int k0) {
#pragma unroll
        for (int n = 0; n < 2; ++n) {
            const int W = wave + n * 4;
            const int r = W * 8 + lr3;
            GLL16(Kbh + (size_t)(k0 + r) * 64 + qcs * 8, &Ks[buf][W * 512]);
            GLL16(Vbh + (size_t)r * 2048 + k0 + qcs * 8, &Vs[buf][W * 512]);
        }
    };

    const unsigned short* Qbase = Qh + ((size_t)bh * 2048 + q0 + wave * 16 + lr) * 64 + quad * 8;
    const short8 qf0 = *(const short8*)Qbase;
    const short8 qf1 = *(const short8*)(Qbase + 32);

    short8 onesA;
#pragma unroll
    for (int j = 0; j < 8; j++) onesA[j] = (short)0x3F80;

    f32x4 o[4];
    f32x4 lacc = (f32x4){0.f, 0.f, 0.f, 0.f};
#pragma unroll
    for (int nt = 0; nt < 4; nt++) o[nt] = (f32x4){0.f, 0.f, 0.f, 0.f};

    const int srcA = (quad & 1) * 32 + lr;
    const int srcB = srcA + 16;

    stage(0, 0);

    for (int it = 0; it < 32; ++it) {
        __syncthreads();
        if (it + 1 < 32) stage((it + 1) & 1, (it + 1) * 64);
        const unsigned short* Kb = Ks[it & 1];
        const unsigned short* Vb = Vs[it & 1];
        const int k0 = it * 64;
#pragma unroll
        for (int s32 = 0; s32 < 2; ++s32) {
            unsigned int pk[2][2];
#pragma unroll
            for (int tt = 0; tt < 2; ++tt) {
                const int kk = (s32 * 2 + tt) * 16 + lr;
                const short8 kf0 = *(const short8*)&Kb[(kk * 8 + (quad ^ (kk & 7))) * 8];
                const short8 kf1 = *(const short8*)&Kb[(kk * 8 + ((quad + 4) ^ (kk & 7))) * 8];
                f32x4 z = (f32x4){0.f, 0.f, 0.f, 0.f};
                z = MFMA16(kf0, qf0, z);
                z = MFMA16(kf1, qf1, z);
                const f32x4 mv = *(const f32x4*)&maskl[k0 + (s32 * 2 + tt) * 16 + quad * 4];
                const float p0 = __builtin_amdgcn_exp2f(z[0]) * mv[0];
                const float p1 = __builtin_amdgcn_exp2f(z[1]) * mv[1];
                const float p2 = __builtin_amdgcn_exp2f(z[2]) * mv[2];
                const float p3 = __builtin_amdgcn_exp2f(z[3]) * mv[3];
                pk[tt][0] = ((unsigned)f2bf(p1) << 16) | f2bf(p0);
                pk[tt][1] = ((unsigned)f2bf(p3) << 16) | f2bf(p2);
            }
            const int a0 = __shfl((int)pk[0][0], srcA, 64);
            const int a1 = __shfl((int)pk[0][1], srcA, 64);
            const int a2 = __shfl((int)pk[0][0], srcB, 64);
            const int a3 = __shfl((int)pk[0][1], srcB, 64);
            const int c0 = __shfl((int)pk[1][0], srcA, 64);
            const int c1 = __shfl((int)pk[1][1], srcA, 64);
            const int c2 = __shfl((int)pk[1][0], srcB, 64);
            const int c3 = __shfl((int)pk[1][1], srcB, 64);
            const bool hi = quad >= 2;
            union { int32x4 i; short8 s; } u;
            u.i = (int32x4){hi ? c0 : a0, hi ? c1 : a1, hi ? c2 : a2, hi ? c3 : a3};
            const short8 pb = u.s;

            lacc = MFMA16(onesA, pb, lacc);
#pragma unroll
            for (int nt = 0; nt < 4; ++nt) {
                const int d = nt * 16 + lr;
                const int qc = s32 * 4 + quad;
                const short8 vf = *(const short8*)&Vb[(d * 8 + (qc ^ (d & 7))) * 8];
                o[nt] = MFMA16(vf, pb, o[nt]);
            }
        }
    }

    const float linv = 1.f / lacc[0];
    const int srow = q0 + wave * 16 + lr;
#pragma unroll
    for (int nt = 0; nt < 4; ++nt) {
        ushort4 pk4;
        pk4.x = f2bf(o[nt][0] * linv);
        pk4.y = f2bf(o[nt][1] * linv);
        pk4.z = f2bf(o[nt][2] * linv);
        pk4.w = f2bf(o[nt][3] * linv);
        *(ushort4*)&ctx[((size_t)(b * 2048 + srow)) * 1024 + h * 64 + nt * 16 + quad * 4] = pk4;
    }
}

extern "C" void kernel_launch(void* const* d_in, const int* in_sizes, int n_in,
                              void* d_out, int out_size, void* d_ws, size_t ws_size,
                              hipStream_t stream)
{
    const float* query = (const float*)d_in[0];
    const float* key_  = (const float*)d_in[1];
    const float* value = (const float*)d_in[2];
    const int* kpm     = (const int*)d_in[3];
    const int* am      = (const int*)d_in[4];
    const float* Wq = (const float*)d_in[6];
    const float* bq = (const float*)d_in[7];
    const float* Wk = (const float*)d_in[8];
    const float* bk = (const float*)d_in[9];
    const float* Wv = (const float*)d_in[10];
    const float* bv = (const float*)d_in[11];
    const float* Wo = (const float*)d_in[12];
    const float* bo = (const float*)d_in[13];

    unsigned short* ws16 = (unsigned short*)d_ws;
    unsigned short* Qh  = ws16;                         // 4M ushorts
    unsigned short* Kh  = ws16 + (1u << 22);            // 4M
    unsigned short* Vt  = ws16 + (2u << 22);            // 4M
    unsigned short* ctx = ws16 + 3 * (1u << 22);        // 4M

    unsigned short* ob  = (unsigned short*)d_out;       // 8M ushorts of scratch
    unsigned short* qb  = ob;                           // 4M
    unsigned short* kb  = ob + (1u << 22);              // 4M
    unsigned short* vb  = ob;                           // reuses qb after QK-GEMM

    const dim3 blk(256);
    const float alpha_q = 0.125f * 1.4426950408889634f; // fold 1/sqrt(64) and log2(e) into Q

    conv_cast2<<<dim3(2048, 2), blk, 0, stream>>>(query, qb, key_, kb);
    gemm_qk<<<1024, blk, 0, stream>>>(qb, Wq, bq, alpha_q, (void*)Qh, kb, Wk, bk, (void*)Kh);
    conv_cast2<<<dim3(2048, 1), blk, 0, stream>>>(value, vb, nullptr, nullptr);
    gemm_one<2><<<512, blk, 0, stream>>>(vb, Wv, bv, 1.0f, (void*)Vt);
    attn_kernel<<<dim3(32, 32), blk, 0, stream>>>(Qh, Kh, Vt, kpm, am, ctx);
    gemm_one<0><<<512, blk, 0, stream>>>(ctx, Wo, bo, 1.0f, d_out);
}